// Round 15
// baseline (213.869 us; speedup 1.0000x reference)
//
#include <hip/hip_runtime.h>
#include <hip/hip_bf16.h>

#define NB 4096
#define NS 200
#define NE 64
#define NROWS (NB*NS)   // 819200

typedef __attribute__((ext_vector_type(8))) short bf16x8;
typedef __attribute__((ext_vector_type(4))) float f32x4;

__device__ __forceinline__ float bf2f(unsigned v) {
    return __uint_as_float(v << 16);
}
__device__ __forceinline__ unsigned f2bf(float x) {
    unsigned u = __float_as_uint(x);
    u = u + 0x7fffu + ((u >> 16) & 1u);
    return u >> 16;
}

// ------- prep: zero slotted stats (blocks 0-143), W2 split (block 144) -------
__global__ __launch_bounds__(256) void k_prep(const float* __restrict__ W2,
                                              float* __restrict__ stats,
                                              unsigned short* __restrict__ W2h,
                                              unsigned short* __restrict__ W2l) {
    const int t = threadIdx.x, bb = blockIdx.x;
    if (bb < 144) { stats[bb*256 + t] = 0.f; return; }
    #pragma unroll
    for (int r = 0; r < 8; ++r) {
        int idx = r*256 + t;
        int k = idx >> 5, j = idx & 31;
        float v = W2[idx];
        unsigned hb = f2bf(v);
        W2h[j*64 + k] = (unsigned short)hb;
        W2l[j*64 + k] = (unsigned short)(__float_as_uint(v - bf2f(hb)) >> 16);
    }
}

// ------- k_mq: folded weights M[b] + qW[b], PERMUTED rows; 8 batches/block ---
__global__ __launch_bounds__(256) void k_mq(const float* __restrict__ query,
        const float* __restrict__ W1, const float* __restrict__ b1,
        unsigned* __restrict__ Mt, float* __restrict__ qW) {
    __shared__ float qs[8][64];
    const int t = threadIdx.x;
    const int b0 = blockIdx.x * 8;
    qs[t >> 6][t & 63]       = query[(size_t)b0*64 + t];
    qs[4 + (t >> 6)][t & 63] = query[(size_t)b0*64 + 256 + t];
    __syncthreads();
    const int j = t >> 2, e0 = (t & 3) * 16;     // true channel j
    const int P = ((j>>5)&1)*32 + ((j>>2)&1)*16 + ((j>>3)&3)*4 + (j&3);
    float dW[16], sW[16], w3[16];
    #pragma unroll
    for (int ee = 0; ee < 16; ++ee) {
        const int e = e0 + ee;
        float w0  = W1[(size_t)e*64 + j];
        float w1v = W1[(size_t)(64+e)*64 + j];
        float w2v = W1[(size_t)(128+e)*64 + j];
        w3[ee]    = W1[(size_t)(192+e)*64 + j];
        dW[ee] = w1v - w2v;
        sW[ee] = w0 + w2v;
    }
    const float bj = b1[j];
    #pragma unroll
    for (int bb = 0; bb < 8; ++bb) {
        const int b = b0 + bb;
        float qp = 0.f;
        unsigned wbuf[8];
        #pragma unroll
        for (int ee = 0; ee < 16; ee += 2) {
            float q0 = qs[bb][e0+ee], q1 = qs[bb][e0+ee+1];
            float m0 = fmaf(q0, w3[ee],   dW[ee]);
            float m1 = fmaf(q1, w3[ee+1], dW[ee+1]);
            qp = fmaf(q0, sW[ee],   qp);
            qp = fmaf(q1, sW[ee+1], qp);
            wbuf[ee >> 1] = f2bf(m0) | (f2bf(m1) << 16);
        }
        uint4* dst = (uint4*)(Mt + (size_t)b*2048 + P*32 + (t & 3)*8);
        dst[0] = make_uint4(wbuf[0], wbuf[1], wbuf[2], wbuf[3]);
        dst[1] = make_uint4(wbuf[4], wbuf[5], wbuf[6], wbuf[7]);
        qp += __shfl_xor(qp, 1, 64);
        qp += __shfl_xor(qp, 2, 64);
        if ((t & 3) == 0) qW[(size_t)b*64 + P] = bj + qp;
    }
}

// hi/lo bf16 split of 8 floats (lo by truncation: error <= 2^-17, negligible)
__device__ __forceinline__ void cvt_hilo(const float4& x, const float4& y,
                                         bf16x8& hi, bf16x8& lo) {
    const float f[8] = {x.x, x.y, x.z, x.w, y.x, y.y, y.z, y.w};
    #pragma unroll
    for (int i = 0; i < 8; ++i) {
        unsigned us = f2bf(f[i]);
        hi[i] = (short)us;
        lo[i] = (short)(__float_as_uint(f[i] - bf2f(us)) >> 16);
    }
}

// one 16-row tile of pass1 (swapped operands; permuted channels; dwordx4 store)
__device__ __forceinline__ void p1_tile(
    const float4& x0, const float4& x1, const float4& x2, const float4& x3,
    const bf16x8 (&Af)[4][2], const float4 (&qw4)[4],
    int sv, bool chk, float (&sacc)[16], float (&qacc)[16],
    unsigned* __restrict__ hb, int h)
{
    bf16x8 Bh0, Bl0, Bh1, Bl1;
    cvt_hilo(x0, x1, Bh0, Bl0);
    cvt_hilo(x2, x3, Bh1, Bl1);
    f32x4 acc[4];
    #pragma unroll
    for (int cg = 0; cg < 4; ++cg) {
        acc[cg] = (f32x4){0.f,0.f,0.f,0.f};
        acc[cg] = __builtin_amdgcn_mfma_f32_16x16x32_bf16(Af[cg][0], Bh0, acc[cg], 0,0,0);
        acc[cg] = __builtin_amdgcn_mfma_f32_16x16x32_bf16(Af[cg][1], Bh1, acc[cg], 0,0,0);
        acc[cg] = __builtin_amdgcn_mfma_f32_16x16x32_bf16(Af[cg][0], Bl0, acc[cg], 0,0,0);
        acc[cg] = __builtin_amdgcn_mfma_f32_16x16x32_bf16(Af[cg][1], Bl1, acc[cg], 0,0,0);
    }
    if (!chk || sv < 200) {
        float v[4][4];
        #pragma unroll
        for (int cg = 0; cg < 4; ++cg) {
            v[cg][0] = acc[cg][0] + qw4[cg].x;
            v[cg][1] = acc[cg][1] + qw4[cg].y;
            v[cg][2] = acc[cg][2] + qw4[cg].z;
            v[cg][3] = acc[cg][3] + qw4[cg].w;
            #pragma unroll
            for (int r = 0; r < 4; ++r) {
                sacc[cg*4+r] += v[cg][r];
                qacc[cg*4+r] = fmaf(v[cg][r], v[cg][r], qacc[cg*4+r]);
            }
        }
        uint4 c0, c1;
        c0.x = f2bf(v[0][0]) | (f2bf(v[0][1]) << 16);
        c0.y = f2bf(v[0][2]) | (f2bf(v[0][3]) << 16);
        c0.z = f2bf(v[1][0]) | (f2bf(v[1][1]) << 16);
        c0.w = f2bf(v[1][2]) | (f2bf(v[1][3]) << 16);
        c1.x = f2bf(v[2][0]) | (f2bf(v[2][1]) << 16);
        c1.y = f2bf(v[2][2]) | (f2bf(v[2][3]) << 16);
        c1.z = f2bf(v[3][0]) | (f2bf(v[3][1]) << 16);
        c1.w = f2bf(v[3][2]) | (f2bf(v[3][3]) << 16);
        *(uint4*)&hb[(size_t)sv*32 + 4*h]      = c0;
        *(uint4*)&hb[(size_t)sv*32 + 16 + 4*h] = c1;
    }
}

// ------- k_p1g: h1 = facts @ M[b] + qW[b]; 3-deep pipeline; slotted stats ----
__global__ __launch_bounds__(256) void k_p1g(const float* __restrict__ facts,
        const unsigned* __restrict__ Mt, const float* __restrict__ qW,
        float* __restrict__ gsumS, float* __restrict__ gsqS,
        unsigned* __restrict__ h1w) {
    __shared__ float sred[4][128];
    const int b = blockIdx.x, t = threadIdx.x;
    const int l = t & 63, w = t >> 6;
    const int lo4 = l & 15, h = l >> 4;

    const unsigned* mb = Mt + (size_t)b*2048;
    bf16x8 Af[4][2];
    #pragma unroll
    for (int cg = 0; cg < 4; ++cg)
        #pragma unroll
        for (int ks = 0; ks < 2; ++ks)
            Af[cg][ks] = *(const bf16x8*)&mb[(cg*16 + lo4)*32 + ks*16 + 4*h];
    float4 qw4[4];
    #pragma unroll
    for (int cg = 0; cg < 4; ++cg)
        qw4[cg] = *(const float4*)&qW[(size_t)b*64 + cg*16 + 4*h];

    const float* fb = facts + (size_t)b*(NS*NE) + 8*h;
    unsigned* hb = h1w + (size_t)b*200*32;

    float sacc[16], qacc[16];
    #pragma unroll
    for (int i = 0; i < 16; ++i) { sacc[i] = 0.f; qacc[i] = 0.f; }

#define P1L(RT, X0, X1, X2, X3, CHK) do { \
    const int sv_ = (RT)*16 + lo4; \
    if (!(CHK) || sv_ < 200) { \
        const float* p_ = fb + (size_t)sv_*64; \
        X0 = *(const float4*)(p_);      X1 = *(const float4*)(p_+4); \
        X2 = *(const float4*)(p_+32);   X3 = *(const float4*)(p_+36); \
    } else { X0 = X1 = X2 = X3 = make_float4(0.f,0.f,0.f,0.f); } \
} while(0)
#define P1P(RT, X0, X1, X2, X3, CHK) \
    p1_tile(X0, X1, X2, X3, Af, qw4, (RT)*16 + lo4, CHK, sacc, qacc, hb, h)

    float4 A0,A1,A2,A3, B0,B1,B2,B3, C0,C1,C2_,C3;
    const bool h3 = (w == 0);
    P1L(w,     A0,A1,A2,A3, false);
    P1L(w + 4, B0,B1,B2,B3, false);
    P1L(w + 8, C0,C1,C2_,C3, false);
    P1P(w,     A0,A1,A2,A3, false);
    if (h3) P1L(12, A0,A1,A2,A3, true);
    P1P(w + 4, B0,B1,B2,B3, false);
    P1P(w + 8, C0,C1,C2_,C3, false);
    if (h3) P1P(12, A0,A1,A2,A3, true);
#undef P1L
#undef P1P

    #pragma unroll
    for (int cg = 0; cg < 4; ++cg) {
        #pragma unroll
        for (int r = 0; r < 4; ++r) {
            const int i = cg*4 + r;
            float s = sacc[i], q = qacc[i];
            s += __shfl_xor(s, 1, 64); s += __shfl_xor(s, 2, 64);
            s += __shfl_xor(s, 4, 64); s += __shfl_xor(s, 8, 64);
            q += __shfl_xor(q, 1, 64); q += __shfl_xor(q, 2, 64);
            q += __shfl_xor(q, 4, 64); q += __shfl_xor(q, 8, 64);
            if (lo4 == 0) {
                const int ch = 32*(cg>>1) + 4*(cg&1) + 8*h + r;
                sred[w][ch] = s; sred[w][64 + ch] = q;
            }
        }
    }
    __syncthreads();
    if (t < 128) {
        const int slot = b & 255;
        float v = sred[0][t] + sred[1][t] + sred[2][t] + sred[3][t];
        if (t < 64) atomicAdd(gsumS + slot*64 + t, v);
        else        atomicAdd(gsqS  + slot*64 + (t - 64), v);
    }
}

// -------- finalize: sum slots, fold BN+Dice into per-channel A,B,G,H ---------
__global__ __launch_bounds__(64) void k_fin(const float* __restrict__ gsumS,
        const float* __restrict__ gsqS, int S,
        const float* __restrict__ gam, const float* __restrict__ bet,
        const float* __restrict__ dg, const float* __restrict__ db,
        float* __restrict__ C, int n) {
    int j = threadIdx.x;
    if (j >= n) return;
    float sum = 0.f, sq = 0.f;
    #pragma unroll 8
    for (int s = 0; s < S; ++s) {
        sum += gsumS[s*n + j];
        sq  += gsqS[s*n + j];
    }
    const float Ninv = 1.0f / (float)NROWS;
    float m = sum * Ninv;
    float v = fmaxf(sq*Ninv - m*m, 0.f);
    float rstd = rsqrtf(v + 1e-5f);
    float A = gam[j] * rstd;
    float Bc = bet[j] - A*m;
    float vard = A*A*v;                   // = gamma^2 * v/(v+eps)
    float rstdd = rsqrtf(vard + 1e-8f);
    float G = dg[j] * rstdd * A;
    float H = db[j] - G*m;
    C[j] = A; C[n+j] = Bc; C[2*n+j] = G; C[3*n+j] = H;
}

// dice on 8 bf16 channels -> hi/lo bf16 fragments (lo by truncation)
__device__ __forceinline__ void dice8(const bf16x8& hv, int k0, const float* Cs,
                                      bf16x8& Bh, bf16x8& Bl) {
    #pragma unroll
    for (int i = 0; i < 8; ++i) {
        const int k = k0 + i;
        float h = bf2f((unsigned short)hv[i]);
        float x  = fmaf(Cs[k],     h, Cs[64+k]);
        float tg = fmaf(Cs[128+k], h, Cs[192+k]);
        float gate = __builtin_amdgcn_rcpf(1.f + __expf(-tg));
        float fac = fmaf(gate, Cs[256+k], Cs[320+k]);   // gate*(1-al)+al
        float hd = x * fac;
        unsigned us = f2bf(hd);
        Bh[i] = (short)us;
        Bl[i] = (short)(__float_as_uint(hd - bf2f(us)) >> 16);
    }
}

// --- pass2 (MFMA, swapped): h2^T = W2^T @ dice(h1)^T; mask-predicated store --
__global__ __launch_bounds__(256) void k_pass2(const unsigned short* __restrict__ h1u,
        const float* __restrict__ C1, const float* __restrict__ a1,
        const unsigned short* __restrict__ W2h, const unsigned short* __restrict__ W2l,
        const float* __restrict__ b2, const int* __restrict__ mask,
        unsigned* __restrict__ h2w,
        float* __restrict__ gsum2S, float* __restrict__ gsq2S) {
    __shared__ float Cs[384];
    __shared__ float sred[4][64];
    const int t = threadIdx.x;
    const int l = t & 63, w = t >> 6;
    const int lo4 = l & 15, hi4 = l >> 4;
    Cs[t] = C1[t];
    if (t < 64) { Cs[256 + t] = 1.f - a1[t]; Cs[320 + t] = a1[t]; }
    __syncthreads();

    bf16x8 Ah[2][2], Al[2][2];
    #pragma unroll
    for (int cg = 0; cg < 2; ++cg) {
        const int col = cg*16 + lo4;
        #pragma unroll
        for (int ks = 0; ks < 2; ++ks) {
            const int k0 = ks*32 + 8*hi4;
            Ah[cg][ks] = *(const bf16x8*)&W2h[col*64 + k0];
            Al[cg][ks] = *(const bf16x8*)&W2l[col*64 + k0];
        }
    }
    float4 b24[2];
    #pragma unroll
    for (int cg = 0; cg < 2; ++cg)
        b24[cg] = *(const float4*)&b2[cg*16 + 4*hi4];

    float s2[8], q2[8];
    #pragma unroll
    for (int i = 0; i < 8; ++i) { s2[i] = 0.f; q2[i] = 0.f; }
    const int rbase0 = blockIdx.x*256 + w*64;   // 4 tiles of 16 rows per wave

#define P2_LOAD(TT, H0, H1, MK) do { \
    const int s_ = rbase0 + (TT)*16 + lo4; \
    H0 = *(const bf16x8*)&h1u[(size_t)s_*64 + 8*hi4]; \
    H1 = *(const bf16x8*)&h1u[(size_t)s_*64 + 32 + 8*hi4]; \
    MK = mask[s_]; \
} while(0)

#define P2_PROC(TT, H0, H1, MK) do { \
    bf16x8 Bh0, Bl0, Bh1, Bl1; \
    dice8(H0, 8*hi4,      Cs, Bh0, Bl0); \
    dice8(H1, 32 + 8*hi4, Cs, Bh1, Bl1); \
    f32x4 a_[2]; \
    _Pragma("unroll") \
    for (int cg = 0; cg < 2; ++cg) { \
        a_[cg] = (f32x4){0.f,0.f,0.f,0.f}; \
        a_[cg] = __builtin_amdgcn_mfma_f32_16x16x32_bf16(Ah[cg][0], Bh0, a_[cg], 0,0,0); \
        a_[cg] = __builtin_amdgcn_mfma_f32_16x16x32_bf16(Ah[cg][1], Bh1, a_[cg], 0,0,0); \
        a_[cg] = __builtin_amdgcn_mfma_f32_16x16x32_bf16(Al[cg][0], Bh0, a_[cg], 0,0,0); \
        a_[cg] = __builtin_amdgcn_mfma_f32_16x16x32_bf16(Al[cg][1], Bh1, a_[cg], 0,0,0); \
        a_[cg] = __builtin_amdgcn_mfma_f32_16x16x32_bf16(Ah[cg][0], Bl0, a_[cg], 0,0,0); \
        a_[cg] = __builtin_amdgcn_mfma_f32_16x16x32_bf16(Ah[cg][1], Bl1, a_[cg], 0,0,0); \
    } \
    const int s_ = rbase0 + (TT)*16 + lo4; \
    _Pragma("unroll") \
    for (int cg = 0; cg < 2; ++cg) { \
        float v0 = a_[cg][0] + b24[cg].x; \
        float v1 = a_[cg][1] + b24[cg].y; \
        float v2 = a_[cg][2] + b24[cg].z; \
        float v3 = a_[cg][3] + b24[cg].w; \
        s2[cg*4+0] += v0; q2[cg*4+0] = fmaf(v0, v0, q2[cg*4+0]); \
        s2[cg*4+1] += v1; q2[cg*4+1] = fmaf(v1, v1, q2[cg*4+1]); \
        s2[cg*4+2] += v2; q2[cg*4+2] = fmaf(v2, v2, q2[cg*4+2]); \
        s2[cg*4+3] += v3; q2[cg*4+3] = fmaf(v3, v3, q2[cg*4+3]); \
        if (MK > 0) { \
            uint2 pv; \
            pv.x = f2bf(v0) | (f2bf(v1) << 16); \
            pv.y = f2bf(v2) | (f2bf(v3) << 16); \
            *(uint2*)&h2w[(size_t)s_*16 + 8*cg + 2*hi4] = pv; \
        } \
    } \
} while(0)

    bf16x8 X0, X1, Y0, Y1;
    int mkX, mkY;
    P2_LOAD(0, X0, X1, mkX);
    P2_LOAD(1, Y0, Y1, mkY);
    P2_PROC(0, X0, X1, mkX);
    P2_LOAD(2, X0, X1, mkX);
    P2_PROC(1, Y0, Y1, mkY);
    P2_LOAD(3, Y0, Y1, mkY);
    P2_PROC(2, X0, X1, mkX);
    P2_PROC(3, Y0, Y1, mkY);
#undef P2_LOAD
#undef P2_PROC

    #pragma unroll
    for (int i = 0; i < 8; ++i) {
        float s = s2[i], q = q2[i];
        s += __shfl_xor(s, 1, 64); s += __shfl_xor(s, 2, 64);
        s += __shfl_xor(s, 4, 64); s += __shfl_xor(s, 8, 64);
        q += __shfl_xor(q, 1, 64); q += __shfl_xor(q, 2, 64);
        q += __shfl_xor(q, 4, 64); q += __shfl_xor(q, 8, 64);
        if (lo4 == 0) {
            const int ch = (i >> 2)*16 + 4*hi4 + (i & 3);
            sred[w][ch] = s; sred[w][32 + ch] = q;
        }
    }
    __syncthreads();
    if (t < 64) {
        const int slot = blockIdx.x & 63;
        float v = sred[0][t] + sred[1][t] + sred[2][t] + sred[3][t];
        if (t < 32) atomicAdd(gsum2S + slot*32 + t, v);
        else        atomicAdd(gsq2S  + slot*32 + (t - 32), v);
    }
}

// ------- pass3: mask-predicated h2 read + scores + softmax + compacted sum ---
__device__ __forceinline__ float wsum(float v) {
    #pragma unroll
    for (int m = 32; m; m >>= 1) v += __shfl_xor(v, m, 64);
    return v;
}
__device__ __forceinline__ float wmax(float v) {
    #pragma unroll
    for (int m = 32; m; m >>= 1) v = fmaxf(v, __shfl_xor(v, m, 64));
    return v;
}
__global__ __launch_bounds__(256) void k_pass3(const unsigned* __restrict__ h2p,
        const float* __restrict__ C2, const float* __restrict__ a2,
        const float* __restrict__ Wf, const float* __restrict__ bfp,
        const int* __restrict__ mask, const float* __restrict__ facts,
        float* __restrict__ out) {
    __shared__ float rmax[4], rsum[4], wgt[256], par[4][64];
    __shared__ int idxs[200];
    __shared__ int cnt;
    const int b = blockIdx.x, t = threadIdx.x;
    if (t == 0) cnt = 0;
    float score = -1e30f;
    bool msk = false;
    if (t < NS) {
        size_t g = (size_t)b*NS + t;
        msk = (mask[g] > 0);
        score = -1e9f;
        if (msk) {
            const uint4* hv = (const uint4*)(h2p + g*16);
            uint4 U0 = hv[0], U1 = hv[1], U2 = hv[2], U3 = hv[3];
            unsigned uw[16] = {U0.x,U0.y,U0.z,U0.w, U1.x,U1.y,U1.z,U1.w,
                               U2.x,U2.y,U2.z,U2.w, U3.x,U3.y,U3.z,U3.w};
            float acc = bfp[0];
            #pragma unroll
            for (int jp = 0; jp < 16; ++jp) {
                unsigned u = uw[jp];
                #pragma unroll
                for (int h = 0; h < 2; ++h) {
                    int k = 2*jp + h;
                    float hval = bf2f(h ? (u >> 16) : (u & 0xffffu));
                    float x  = fmaf(C2[k],    hval, C2[32+k]);
                    float tg = fmaf(C2[64+k], hval, C2[96+k]);
                    float gate = __builtin_amdgcn_rcpf(1.f + __expf(-tg));
                    float al = a2[k];
                    acc = fmaf(x * fmaf(gate, 1.f - al, al), Wf[k], acc);
                }
            }
            score = acc;
        }
    }
    float m = wmax(score);
    if ((t & 63) == 0) rmax[t >> 6] = m;
    __syncthreads();
    m = fmaxf(fmaxf(rmax[0],rmax[1]), fmaxf(rmax[2],rmax[3]));
    float ee = __expf(score - m);
    float zs = wsum(ee);
    if ((t & 63) == 0) rsum[t >> 6] = zs;
    __syncthreads();
    float Z = rsum[0]+rsum[1]+rsum[2]+rsum[3];
    wgt[t] = ee * __builtin_amdgcn_rcpf(Z);
    if (msk) {                       // masked rows have wgt exactly 0 -> skip
        int pos = atomicAdd(&cnt, 1);
        idxs[pos] = t;
    }
    __syncthreads();
    const int n = cnt;
    const int e = t & 63, p = t >> 6;
    const float* fbp = facts + (size_t)b*(NS*NE) + e;
    float a0 = 0.f, a1 = 0.f;
    int i = p;
    for (; i + 4 < n; i += 8) {
        const int s0 = idxs[i], s1 = idxs[i + 4];
        a0 = fmaf(wgt[s0], fbp[(size_t)s0*64], a0);
        a1 = fmaf(wgt[s1], fbp[(size_t)s1*64], a1);
    }
    if (i < n) {
        const int s0 = idxs[i];
        a0 = fmaf(wgt[s0], fbp[(size_t)s0*64], a0);
    }
    par[p][e] = a0 + a1;
    __syncthreads();
    if (t < 64) out[(size_t)b*64 + t] = par[0][t]+par[1][t]+par[2][t]+par[3][t];
}

extern "C" void kernel_launch(void* const* d_in, const int* in_sizes, int n_in,
                              void* d_out, int out_size, void* d_ws, size_t ws_size,
                              hipStream_t stream) {
    const float* query = (const float*)d_in[0];
    const float* facts = (const float*)d_in[1];
    const int*   mask  = (const int*)d_in[2];
    const float* W1  = (const float*)d_in[3];
    const float* b1  = (const float*)d_in[4];
    const float* g1  = (const float*)d_in[5];
    const float* be1 = (const float*)d_in[6];
    const float* dg1 = (const float*)d_in[7];
    const float* db1 = (const float*)d_in[8];
    const float* a1  = (const float*)d_in[9];
    const float* W2  = (const float*)d_in[10];
    const float* b2  = (const float*)d_in[11];
    const float* g2  = (const float*)d_in[12];
    const float* be2 = (const float*)d_in[13];
    const float* dg2 = (const float*)d_in[14];
    const float* db2 = (const float*)d_in[15];
    const float* a2  = (const float*)d_in[16];
    const float* Wf  = (const float*)d_in[17];
    const float* bff = (const float*)d_in[18];
    float* out = (float*)d_out;

    float* ws = (float*)d_ws;
    float* gsum1s = ws + 0;       // 256 slots x 64 = 16384
    float* gsq1s  = ws + 16384;   // 16384
    float* gsum2s = ws + 32768;   // 64 slots x 32 = 2048
    float* gsq2s  = ws + 34816;   // 2048  (stats = ws[0..36864), zeroed by k_prep)
    float* C1     = ws + 36864;   // 256
    float* C2     = ws + 37120;   // 128
    unsigned short* W2h = (unsigned short*)(ws + 37376);  // 2048 u16
    unsigned short* W2l = (unsigned short*)(ws + 38400);  // 2048 u16
    unsigned* h1p = (unsigned*)(ws + 40960);         // NROWS*32 u32 = 105 MB
    unsigned* h2p = h1p + (size_t)NROWS*32;          // NROWS*16 u32 = 52 MB
    // Mt/qW alias the h2 region (dead until k_pass2 writes it)
    unsigned* Mt = h2p;                               // 4096*2048 u32 = 33.5 MB
    float* qWb   = (float*)(h2p + (size_t)NB*2048);   // 4096*64 f32 = 1 MB
    (void)ws_size; (void)in_sizes; (void)n_in; (void)out_size;

    k_prep<<<145, 256, 0, stream>>>(W2, ws, W2h, W2l);
    k_mq<<<NB/8, 256, 0, stream>>>(query, W1, b1, Mt, qWb);
    k_p1g<<<NB, 256, 0, stream>>>(facts, Mt, qWb, gsum1s, gsq1s, h1p);
    k_fin<<<1, 64, 0, stream>>>(gsum1s, gsq1s, 256, g1, be1, dg1, db1, C1, 64);
    k_pass2<<<NROWS/256, 256, 0, stream>>>((const unsigned short*)h1p, C1, a1,
                                           W2h, W2l, b2, mask,
                                           h2p, gsum2s, gsq2s);
    k_fin<<<1, 32, 0, stream>>>(gsum2s, gsq2s, 64, g2, be2, dg2, db2, C2, 32);
    k_pass3<<<NB, 256, 0, stream>>>(h2p, C2, a2, Wf, bff, mask, facts, out);
}

// Round 16
// 206.427 us; speedup vs baseline: 1.0361x; 1.0361x over previous
//
#include <hip/hip_runtime.h>
#include <hip/hip_bf16.h>

#define NB 4096
#define NS 200
#define NE 64
#define NROWS (NB*NS)   // 819200

typedef __attribute__((ext_vector_type(8))) short bf16x8;
typedef __attribute__((ext_vector_type(4))) float f32x4;

__device__ __forceinline__ float bf2f(unsigned v) {
    return __uint_as_float(v << 16);
}
__device__ __forceinline__ unsigned f2bf(float x) {
    unsigned u = __float_as_uint(x);
    u = u + 0x7fffu + ((u >> 16) & 1u);
    return u >> 16;
}

// ------- prep: zero slotted stats (blocks 0-143), W2 split (block 144) -------
__global__ __launch_bounds__(256) void k_prep(const float* __restrict__ W2,
                                              float* __restrict__ stats,
                                              unsigned short* __restrict__ W2h,
                                              unsigned short* __restrict__ W2l) {
    const int t = threadIdx.x, bb = blockIdx.x;
    if (bb < 144) { stats[bb*256 + t] = 0.f; return; }
    #pragma unroll
    for (int r = 0; r < 8; ++r) {
        int idx = r*256 + t;
        int k = idx >> 5, j = idx & 31;
        float v = W2[idx];
        unsigned hb = f2bf(v);
        W2h[j*64 + k] = (unsigned short)hb;
        W2l[j*64 + k] = (unsigned short)(__float_as_uint(v - bf2f(hb)) >> 16);
    }
}

// ------- k_mq: folded weights M[b] + qW[b], PERMUTED rows; 8 batches/block ---
__global__ __launch_bounds__(256) void k_mq(const float* __restrict__ query,
        const float* __restrict__ W1, const float* __restrict__ b1,
        unsigned* __restrict__ Mt, float* __restrict__ qW) {
    __shared__ float qs[8][64];
    const int t = threadIdx.x;
    const int b0 = blockIdx.x * 8;
    qs[t >> 6][t & 63]       = query[(size_t)b0*64 + t];
    qs[4 + (t >> 6)][t & 63] = query[(size_t)b0*64 + 256 + t];
    __syncthreads();
    const int j = t >> 2, e0 = (t & 3) * 16;     // true channel j
    const int P = ((j>>5)&1)*32 + ((j>>2)&1)*16 + ((j>>3)&3)*4 + (j&3);
    float dW[16], sW[16], w3[16];
    #pragma unroll
    for (int ee = 0; ee < 16; ++ee) {
        const int e = e0 + ee;
        float w0  = W1[(size_t)e*64 + j];
        float w1v = W1[(size_t)(64+e)*64 + j];
        float w2v = W1[(size_t)(128+e)*64 + j];
        w3[ee]    = W1[(size_t)(192+e)*64 + j];
        dW[ee] = w1v - w2v;
        sW[ee] = w0 + w2v;
    }
    const float bj = b1[j];
    #pragma unroll
    for (int bb = 0; bb < 8; ++bb) {
        const int b = b0 + bb;
        float qp = 0.f;
        unsigned wbuf[8];
        #pragma unroll
        for (int ee = 0; ee < 16; ee += 2) {
            float q0 = qs[bb][e0+ee], q1 = qs[bb][e0+ee+1];
            float m0 = fmaf(q0, w3[ee],   dW[ee]);
            float m1 = fmaf(q1, w3[ee+1], dW[ee+1]);
            qp = fmaf(q0, sW[ee],   qp);
            qp = fmaf(q1, sW[ee+1], qp);
            wbuf[ee >> 1] = f2bf(m0) | (f2bf(m1) << 16);
        }
        uint4* dst = (uint4*)(Mt + (size_t)b*2048 + P*32 + (t & 3)*8);
        dst[0] = make_uint4(wbuf[0], wbuf[1], wbuf[2], wbuf[3]);
        dst[1] = make_uint4(wbuf[4], wbuf[5], wbuf[6], wbuf[7]);
        qp += __shfl_xor(qp, 1, 64);
        qp += __shfl_xor(qp, 2, 64);
        if ((t & 3) == 0) qW[(size_t)b*64 + P] = bj + qp;
    }
}

// hi/lo bf16 split of 8 floats (lo by truncation: error <= 2^-17, negligible)
__device__ __forceinline__ void cvt_hilo(const float4& x, const float4& y,
                                         bf16x8& hi, bf16x8& lo) {
    const float f[8] = {x.x, x.y, x.z, x.w, y.x, y.y, y.z, y.w};
    #pragma unroll
    for (int i = 0; i < 8; ++i) {
        unsigned us = f2bf(f[i]);
        hi[i] = (short)us;
        lo[i] = (short)(__float_as_uint(f[i] - bf2f(us)) >> 16);
    }
}

// one 16-row tile of pass1 (swapped operands; permuted channels; dwordx4 store)
__device__ __forceinline__ void p1_tile(
    const float4& x0, const float4& x1, const float4& x2, const float4& x3,
    const bf16x8 (&Af)[4][2], const float4 (&qw4)[4],
    int sv, bool chk, float (&sacc)[16], float (&qacc)[16],
    unsigned* __restrict__ hb, int h)
{
    bf16x8 Bh0, Bl0, Bh1, Bl1;
    cvt_hilo(x0, x1, Bh0, Bl0);
    cvt_hilo(x2, x3, Bh1, Bl1);
    f32x4 acc[4];
    #pragma unroll
    for (int cg = 0; cg < 4; ++cg) {
        acc[cg] = (f32x4){0.f,0.f,0.f,0.f};
        acc[cg] = __builtin_amdgcn_mfma_f32_16x16x32_bf16(Af[cg][0], Bh0, acc[cg], 0,0,0);
        acc[cg] = __builtin_amdgcn_mfma_f32_16x16x32_bf16(Af[cg][1], Bh1, acc[cg], 0,0,0);
        acc[cg] = __builtin_amdgcn_mfma_f32_16x16x32_bf16(Af[cg][0], Bl0, acc[cg], 0,0,0);
        acc[cg] = __builtin_amdgcn_mfma_f32_16x16x32_bf16(Af[cg][1], Bl1, acc[cg], 0,0,0);
    }
    if (!chk || sv < 200) {
        float v[4][4];
        #pragma unroll
        for (int cg = 0; cg < 4; ++cg) {
            v[cg][0] = acc[cg][0] + qw4[cg].x;
            v[cg][1] = acc[cg][1] + qw4[cg].y;
            v[cg][2] = acc[cg][2] + qw4[cg].z;
            v[cg][3] = acc[cg][3] + qw4[cg].w;
            #pragma unroll
            for (int r = 0; r < 4; ++r) {
                sacc[cg*4+r] += v[cg][r];
                qacc[cg*4+r] = fmaf(v[cg][r], v[cg][r], qacc[cg*4+r]);
            }
        }
        uint4 c0, c1;
        c0.x = f2bf(v[0][0]) | (f2bf(v[0][1]) << 16);
        c0.y = f2bf(v[0][2]) | (f2bf(v[0][3]) << 16);
        c0.z = f2bf(v[1][0]) | (f2bf(v[1][1]) << 16);
        c0.w = f2bf(v[1][2]) | (f2bf(v[1][3]) << 16);
        c1.x = f2bf(v[2][0]) | (f2bf(v[2][1]) << 16);
        c1.y = f2bf(v[2][2]) | (f2bf(v[2][3]) << 16);
        c1.z = f2bf(v[3][0]) | (f2bf(v[3][1]) << 16);
        c1.w = f2bf(v[3][2]) | (f2bf(v[3][3]) << 16);
        *(uint4*)&hb[(size_t)sv*32 + 4*h]      = c0;
        *(uint4*)&hb[(size_t)sv*32 + 16 + 4*h] = c1;
    }
}

// ------- k_p1g: h1 = facts @ M[b] + qW[b]; 3-deep pipeline; slotted stats ----
__global__ __launch_bounds__(256) void k_p1g(const float* __restrict__ facts,
        const unsigned* __restrict__ Mt, const float* __restrict__ qW,
        float* __restrict__ gsumS, float* __restrict__ gsqS,
        unsigned* __restrict__ h1w) {
    __shared__ float sred[4][128];
    const int b = blockIdx.x, t = threadIdx.x;
    const int l = t & 63, w = t >> 6;
    const int lo4 = l & 15, h = l >> 4;

    const unsigned* mb = Mt + (size_t)b*2048;
    bf16x8 Af[4][2];
    #pragma unroll
    for (int cg = 0; cg < 4; ++cg)
        #pragma unroll
        for (int ks = 0; ks < 2; ++ks)
            Af[cg][ks] = *(const bf16x8*)&mb[(cg*16 + lo4)*32 + ks*16 + 4*h];
    float4 qw4[4];
    #pragma unroll
    for (int cg = 0; cg < 4; ++cg)
        qw4[cg] = *(const float4*)&qW[(size_t)b*64 + cg*16 + 4*h];

    const float* fb = facts + (size_t)b*(NS*NE) + 8*h;
    unsigned* hb = h1w + (size_t)b*200*32;

    float sacc[16], qacc[16];
    #pragma unroll
    for (int i = 0; i < 16; ++i) { sacc[i] = 0.f; qacc[i] = 0.f; }

#define P1L(RT, X0, X1, X2, X3, CHK) do { \
    const int sv_ = (RT)*16 + lo4; \
    if (!(CHK) || sv_ < 200) { \
        const float* p_ = fb + (size_t)sv_*64; \
        X0 = *(const float4*)(p_);      X1 = *(const float4*)(p_+4); \
        X2 = *(const float4*)(p_+32);   X3 = *(const float4*)(p_+36); \
    } else { X0 = X1 = X2 = X3 = make_float4(0.f,0.f,0.f,0.f); } \
} while(0)
#define P1P(RT, X0, X1, X2, X3, CHK) \
    p1_tile(X0, X1, X2, X3, Af, qw4, (RT)*16 + lo4, CHK, sacc, qacc, hb, h)

    float4 A0,A1,A2,A3, B0,B1,B2,B3, C0,C1,C2_,C3;
    const bool h3 = (w == 0);
    // 3-deep: all three steady tiles in flight before first compute
    P1L(w,     A0,A1,A2,A3, false);
    P1L(w + 4, B0,B1,B2,B3, false);
    P1L(w + 8, C0,C1,C2_,C3, false);
    P1P(w,     A0,A1,A2,A3, false);
    if (h3) P1L(12, A0,A1,A2,A3, true);     // tile 12: 2 computes of cover
    P1P(w + 4, B0,B1,B2,B3, false);
    P1P(w + 8, C0,C1,C2_,C3, false);
    if (h3) P1P(12, A0,A1,A2,A3, true);
#undef P1L
#undef P1P

    #pragma unroll
    for (int cg = 0; cg < 4; ++cg) {
        #pragma unroll
        for (int r = 0; r < 4; ++r) {
            const int i = cg*4 + r;
            float s = sacc[i], q = qacc[i];
            s += __shfl_xor(s, 1, 64); s += __shfl_xor(s, 2, 64);
            s += __shfl_xor(s, 4, 64); s += __shfl_xor(s, 8, 64);
            q += __shfl_xor(q, 1, 64); q += __shfl_xor(q, 2, 64);
            q += __shfl_xor(q, 4, 64); q += __shfl_xor(q, 8, 64);
            if (lo4 == 0) {
                const int ch = 32*(cg>>1) + 4*(cg&1) + 8*h + r;
                sred[w][ch] = s; sred[w][64 + ch] = q;
            }
        }
    }
    __syncthreads();
    if (t < 128) {
        const int slot = b & 255;
        float v = sred[0][t] + sred[1][t] + sred[2][t] + sred[3][t];
        if (t < 64) atomicAdd(gsumS + slot*64 + t, v);
        else        atomicAdd(gsqS  + slot*64 + (t - 64), v);
    }
}

// -------- finalize: sum slots, fold BN+Dice into per-channel A,B,G,H ---------
__global__ __launch_bounds__(64) void k_fin(const float* __restrict__ gsumS,
        const float* __restrict__ gsqS, int S,
        const float* __restrict__ gam, const float* __restrict__ bet,
        const float* __restrict__ dg, const float* __restrict__ db,
        float* __restrict__ C, int n) {
    int j = threadIdx.x;
    if (j >= n) return;
    float sum = 0.f, sq = 0.f;
    #pragma unroll 8
    for (int s = 0; s < S; ++s) {
        sum += gsumS[s*n + j];
        sq  += gsqS[s*n + j];
    }
    const float Ninv = 1.0f / (float)NROWS;
    float m = sum * Ninv;
    float v = fmaxf(sq*Ninv - m*m, 0.f);
    float rstd = rsqrtf(v + 1e-5f);
    float A = gam[j] * rstd;
    float Bc = bet[j] - A*m;
    float vard = A*A*v;                   // = gamma^2 * v/(v+eps)
    float rstdd = rsqrtf(vard + 1e-8f);
    float G = dg[j] * rstdd * A;
    float H = db[j] - G*m;
    C[j] = A; C[n+j] = Bc; C[2*n+j] = G; C[3*n+j] = H;
}

// dice on 8 bf16 channels -> hi/lo bf16 fragments (lo by truncation)
__device__ __forceinline__ void dice8(const bf16x8& hv, int k0, const float* Cs,
                                      bf16x8& Bh, bf16x8& Bl) {
    #pragma unroll
    for (int i = 0; i < 8; ++i) {
        const int k = k0 + i;
        float h = bf2f((unsigned short)hv[i]);
        float x  = fmaf(Cs[k],     h, Cs[64+k]);
        float tg = fmaf(Cs[128+k], h, Cs[192+k]);
        float gate = __builtin_amdgcn_rcpf(1.f + __expf(-tg));
        float fac = fmaf(gate, Cs[256+k], Cs[320+k]);   // gate*(1-al)+al
        float hd = x * fac;
        unsigned us = f2bf(hd);
        Bh[i] = (short)us;
        Bl[i] = (short)(__float_as_uint(hd - bf2f(us)) >> 16);
    }
}

// --- pass2 (MFMA, swapped): h2^T = W2^T @ dice(h1)^T; 4 tiles/wave, slotted --
__global__ __launch_bounds__(256) void k_pass2(const unsigned short* __restrict__ h1u,
        const float* __restrict__ C1, const float* __restrict__ a1,
        const unsigned short* __restrict__ W2h, const unsigned short* __restrict__ W2l,
        const float* __restrict__ b2,
        unsigned* __restrict__ h2w,
        float* __restrict__ gsum2S, float* __restrict__ gsq2S) {
    __shared__ float Cs[384];
    __shared__ float sred[4][64];
    const int t = threadIdx.x;
    const int l = t & 63, w = t >> 6;
    const int lo4 = l & 15, hi4 = l >> 4;
    Cs[t] = C1[t];
    if (t < 64) { Cs[256 + t] = 1.f - a1[t]; Cs[320 + t] = a1[t]; }
    __syncthreads();

    bf16x8 Ah[2][2], Al[2][2];
    #pragma unroll
    for (int cg = 0; cg < 2; ++cg) {
        const int col = cg*16 + lo4;
        #pragma unroll
        for (int ks = 0; ks < 2; ++ks) {
            const int k0 = ks*32 + 8*hi4;
            Ah[cg][ks] = *(const bf16x8*)&W2h[col*64 + k0];
            Al[cg][ks] = *(const bf16x8*)&W2l[col*64 + k0];
        }
    }
    float4 b24[2];
    #pragma unroll
    for (int cg = 0; cg < 2; ++cg)
        b24[cg] = *(const float4*)&b2[cg*16 + 4*hi4];

    float s2[8], q2[8];
    #pragma unroll
    for (int i = 0; i < 8; ++i) { s2[i] = 0.f; q2[i] = 0.f; }
    const int rbase0 = blockIdx.x*256 + w*64;   // 4 tiles of 16 rows per wave

#define P2_LOAD(TT, H0, H1) do { \
    const int s_ = rbase0 + (TT)*16 + lo4; \
    H0 = *(const bf16x8*)&h1u[(size_t)s_*64 + 8*hi4]; \
    H1 = *(const bf16x8*)&h1u[(size_t)s_*64 + 32 + 8*hi4]; \
} while(0)

#define P2_PROC(TT, H0, H1) do { \
    bf16x8 Bh0, Bl0, Bh1, Bl1; \
    dice8(H0, 8*hi4,      Cs, Bh0, Bl0); \
    dice8(H1, 32 + 8*hi4, Cs, Bh1, Bl1); \
    f32x4 a_[2]; \
    _Pragma("unroll") \
    for (int cg = 0; cg < 2; ++cg) { \
        a_[cg] = (f32x4){0.f,0.f,0.f,0.f}; \
        a_[cg] = __builtin_amdgcn_mfma_f32_16x16x32_bf16(Ah[cg][0], Bh0, a_[cg], 0,0,0); \
        a_[cg] = __builtin_amdgcn_mfma_f32_16x16x32_bf16(Ah[cg][1], Bh1, a_[cg], 0,0,0); \
        a_[cg] = __builtin_amdgcn_mfma_f32_16x16x32_bf16(Al[cg][0], Bh0, a_[cg], 0,0,0); \
        a_[cg] = __builtin_amdgcn_mfma_f32_16x16x32_bf16(Al[cg][1], Bh1, a_[cg], 0,0,0); \
        a_[cg] = __builtin_amdgcn_mfma_f32_16x16x32_bf16(Ah[cg][0], Bl0, a_[cg], 0,0,0); \
        a_[cg] = __builtin_amdgcn_mfma_f32_16x16x32_bf16(Ah[cg][1], Bl1, a_[cg], 0,0,0); \
    } \
    const int s_ = rbase0 + (TT)*16 + lo4; \
    _Pragma("unroll") \
    for (int cg = 0; cg < 2; ++cg) { \
        float v0 = a_[cg][0] + b24[cg].x; \
        float v1 = a_[cg][1] + b24[cg].y; \
        float v2 = a_[cg][2] + b24[cg].z; \
        float v3 = a_[cg][3] + b24[cg].w; \
        s2[cg*4+0] += v0; q2[cg*4+0] = fmaf(v0, v0, q2[cg*4+0]); \
        s2[cg*4+1] += v1; q2[cg*4+1] = fmaf(v1, v1, q2[cg*4+1]); \
        s2[cg*4+2] += v2; q2[cg*4+2] = fmaf(v2, v2, q2[cg*4+2]); \
        s2[cg*4+3] += v3; q2[cg*4+3] = fmaf(v3, v3, q2[cg*4+3]); \
        uint2 pv; \
        pv.x = f2bf(v0) | (f2bf(v1) << 16); \
        pv.y = f2bf(v2) | (f2bf(v3) << 16); \
        *(uint2*)&h2w[(size_t)s_*16 + 8*cg + 2*hi4] = pv; \
    } \
} while(0)

    bf16x8 X0, X1, Y0, Y1;
    P2_LOAD(0, X0, X1);
    P2_LOAD(1, Y0, Y1);
    P2_PROC(0, X0, X1);
    P2_LOAD(2, X0, X1);
    P2_PROC(1, Y0, Y1);
    P2_LOAD(3, Y0, Y1);
    P2_PROC(2, X0, X1);
    P2_PROC(3, Y0, Y1);
#undef P2_LOAD
#undef P2_PROC

    #pragma unroll
    for (int i = 0; i < 8; ++i) {
        float s = s2[i], q = q2[i];
        s += __shfl_xor(s, 1, 64); s += __shfl_xor(s, 2, 64);
        s += __shfl_xor(s, 4, 64); s += __shfl_xor(s, 8, 64);
        q += __shfl_xor(q, 1, 64); q += __shfl_xor(q, 2, 64);
        q += __shfl_xor(q, 4, 64); q += __shfl_xor(q, 8, 64);
        if (lo4 == 0) {
            const int ch = (i >> 2)*16 + 4*hi4 + (i & 3);
            sred[w][ch] = s; sred[w][32 + ch] = q;
        }
    }
    __syncthreads();
    if (t < 64) {
        const int slot = blockIdx.x & 63;
        float v = sred[0][t] + sred[1][t] + sred[2][t] + sred[3][t];
        if (t < 32) atomicAdd(gsum2S + slot*32 + t, v);
        else        atomicAdd(gsq2S  + slot*32 + (t - 32), v);
    }
}

// ------- pass3: dice2 + scores + mask + softmax + COMPACTED weighted sum -----
__device__ __forceinline__ float wsum(float v) {
    #pragma unroll
    for (int m = 32; m; m >>= 1) v += __shfl_xor(v, m, 64);
    return v;
}
__device__ __forceinline__ float wmax(float v) {
    #pragma unroll
    for (int m = 32; m; m >>= 1) v = fmaxf(v, __shfl_xor(v, m, 64));
    return v;
}
__global__ __launch_bounds__(256) void k_pass3(const unsigned* __restrict__ h2p,
        const float* __restrict__ C2, const float* __restrict__ a2,
        const float* __restrict__ Wf, const float* __restrict__ bfp,
        const int* __restrict__ mask, const float* __restrict__ facts,
        float* __restrict__ out) {
    __shared__ float rmax[4], rsum[4], wgt[256], par[4][64];
    __shared__ int idxs[200];
    __shared__ int cnt;
    const int b = blockIdx.x, t = threadIdx.x;
    if (t == 0) cnt = 0;
    float score = -1e30f;
    bool msk = false;
    if (t < NS) {
        size_t g = (size_t)b*NS + t;
        msk = (mask[g] > 0);
        const uint4* hv = (const uint4*)(h2p + g*16);
        uint4 U0 = hv[0], U1 = hv[1], U2 = hv[2], U3 = hv[3];
        unsigned uw[16] = {U0.x,U0.y,U0.z,U0.w, U1.x,U1.y,U1.z,U1.w,
                           U2.x,U2.y,U2.z,U2.w, U3.x,U3.y,U3.z,U3.w};
        float acc = bfp[0];
        #pragma unroll
        for (int jp = 0; jp < 16; ++jp) {
            unsigned u = uw[jp];
            #pragma unroll
            for (int h = 0; h < 2; ++h) {
                int k = 2*jp + h;
                float hval = bf2f(h ? (u >> 16) : (u & 0xffffu));
                float x  = fmaf(C2[k],    hval, C2[32+k]);
                float tg = fmaf(C2[64+k], hval, C2[96+k]);
                float gate = __builtin_amdgcn_rcpf(1.f + __expf(-tg));
                float al = a2[k];
                acc = fmaf(x * fmaf(gate, 1.f - al, al), Wf[k], acc);
            }
        }
        score = msk ? acc : -1e9f;
    }
    float m = wmax(score);
    if ((t & 63) == 0) rmax[t >> 6] = m;
    __syncthreads();
    m = fmaxf(fmaxf(rmax[0],rmax[1]), fmaxf(rmax[2],rmax[3]));
    float ee = __expf(score - m);
    float zs = wsum(ee);
    if ((t & 63) == 0) rsum[t >> 6] = zs;
    __syncthreads();
    float Z = rsum[0]+rsum[1]+rsum[2]+rsum[3];
    wgt[t] = ee * __builtin_amdgcn_rcpf(Z);
    if (msk) {                       // masked rows have wgt exactly 0 -> skip
        int pos = atomicAdd(&cnt, 1);
        idxs[pos] = t;
    }
    __syncthreads();
    const int n = cnt;
    const int e = t & 63, p = t >> 6;
    const float* fbp = facts + (size_t)b*(NS*NE) + e;
    float a0 = 0.f, a1 = 0.f;
    int i = p;
    for (; i + 4 < n; i += 8) {
        const int s0 = idxs[i], s1 = idxs[i + 4];
        a0 = fmaf(wgt[s0], fbp[(size_t)s0*64], a0);
        a1 = fmaf(wgt[s1], fbp[(size_t)s1*64], a1);
    }
    if (i < n) {
        const int s0 = idxs[i];
        a0 = fmaf(wgt[s0], fbp[(size_t)s0*64], a0);
    }
    par[p][e] = a0 + a1;
    __syncthreads();
    if (t < 64) out[(size_t)b*64 + t] = par[0][t]+par[1][t]+par[2][t]+par[3][t];
}

extern "C" void kernel_launch(void* const* d_in, const int* in_sizes, int n_in,
                              void* d_out, int out_size, void* d_ws, size_t ws_size,
                              hipStream_t stream) {
    const float* query = (const float*)d_in[0];
    const float* facts = (const float*)d_in[1];
    const int*   mask  = (const int*)d_in[2];
    const float* W1  = (const float*)d_in[3];
    const float* b1  = (const float*)d_in[4];
    const float* g1  = (const float*)d_in[5];
    const float* be1 = (const float*)d_in[6];
    const float* dg1 = (const float*)d_in[7];
    const float* db1 = (const float*)d_in[8];
    const float* a1  = (const float*)d_in[9];
    const float* W2  = (const float*)d_in[10];
    const float* b2  = (const float*)d_in[11];
    const float* g2  = (const float*)d_in[12];
    const float* be2 = (const float*)d_in[13];
    const float* dg2 = (const float*)d_in[14];
    const float* db2 = (const float*)d_in[15];
    const float* a2  = (const float*)d_in[16];
    const float* Wf  = (const float*)d_in[17];
    const float* bff = (const float*)d_in[18];
    float* out = (float*)d_out;

    float* ws = (float*)d_ws;
    float* gsum1s = ws + 0;       // 256 slots x 64 = 16384
    float* gsq1s  = ws + 16384;   // 16384
    float* gsum2s = ws + 32768;   // 64 slots x 32 = 2048
    float* gsq2s  = ws + 34816;   // 2048  (stats = ws[0..36864), zeroed by k_prep)
    float* C1     = ws + 36864;   // 256
    float* C2     = ws + 37120;   // 128
    unsigned short* W2h = (unsigned short*)(ws + 37376);  // 2048 u16
    unsigned short* W2l = (unsigned short*)(ws + 38400);  // 2048 u16
    unsigned* h1p = (unsigned*)(ws + 40960);         // NROWS*32 u32 = 105 MB
    unsigned* h2p = h1p + (size_t)NROWS*32;          // NROWS*16 u32 = 52 MB
    // Mt/qW alias the h2 region (dead until k_pass2 writes it)
    unsigned* Mt = h2p;                               // 4096*2048 u32 = 33.5 MB
    float* qWb   = (float*)(h2p + (size_t)NB*2048);   // 4096*64 f32 = 1 MB
    (void)ws_size; (void)in_sizes; (void)n_in; (void)out_size;

    k_prep<<<145, 256, 0, stream>>>(W2, ws, W2h, W2l);
    k_mq<<<NB/8, 256, 0, stream>>>(query, W1, b1, Mt, qWb);
    k_p1g<<<NB, 256, 0, stream>>>(facts, Mt, qWb, gsum1s, gsq1s, h1p);
    k_fin<<<1, 64, 0, stream>>>(gsum1s, gsq1s, 256, g1, be1, dg1, db1, C1, 64);
    k_pass2<<<NROWS/256, 256, 0, stream>>>((const unsigned short*)h1p, C1, a1,
                                           W2h, W2l, b2,
                                           h2p, gsum2s, gsq2s);
    k_fin<<<1, 32, 0, stream>>>(gsum2s, gsq2s, 64, g2, be2, dg2, db2, C2, 32);
    k_pass3<<<NB, 256, 0, stream>>>(h2p, C2, a2, Wf, bff, mask, facts, out);
}